// Round 1
// baseline (102.690 us; speedup 1.0000x reference)
//
#include <hip/hip_runtime.h>
#include <cmath>

#define BB 64
#define KK 100
#define QQ 100
#define CC 82
#define AA 118
#define KP1 101
#define AM1 117

// Kernel 1: per (b,k): softmax scores/labels, scaled boxes.
__global__ void score_box_kernel(const float* __restrict__ logits,   // B,K,C
                                 const float* __restrict__ boxes_in, // B,K,4
                                 const int*   __restrict__ tsizes,   // B,2
                                 float* __restrict__ out_scores,     // B,K
                                 float* __restrict__ out_labels,     // B,K
                                 float* __restrict__ out_boxes) {    // B,K,4
    int b = blockIdx.x;
    int k = threadIdx.x;
    if (k >= KK) return;
    const float* l = logits + ((size_t)b * KK + k) * CC;
    float m = -INFINITY;
    #pragma unroll 2
    for (int c = 0; c < CC; ++c) m = fmaxf(m, l[c]);
    float denom = 0.f;
    float best = -INFINITY;
    int bi = 0;
    for (int c = 0; c < CC; ++c) {
        float v = l[c];
        denom += expf(v - m);
        if (c < CC - 1 && v > best) { best = v; bi = c; }
    }
    float score = expf(best - m) / denom;
    out_scores[b * KK + k] = score;
    out_labels[b * KK + k] = (float)bi;

    const float* bx = boxes_in + ((size_t)b * KK + k) * 4;
    float cx = bx[0], cy = bx[1], w = bx[2], h = bx[3];
    float ih = (float)tsizes[b * 2 + 0];
    float iw = (float)tsizes[b * 2 + 1];
    float* ob = out_boxes + ((size_t)b * KK + k) * 4;
    ob[0] = (cx - 0.5f * w) * iw;
    ob[1] = (cy - 0.5f * h) * ih;
    ob[2] = (cx + 0.5f * w) * iw;
    ob[3] = (cy + 0.5f * h) * ih;
}

// Kernel 2: per batch block. Phase 1: per-query argmax(hidx), argmax(oidx),
// ms = 1 - sigmoid(last action). Phase 2: winner per segment (O(Q^2) in LDS).
// Phase 3: masked scatter with atomicAdd into zero-initialized pair_score.
__global__ void pair_kernel(const float* __restrict__ actions, // B,Q,A
                            const float* __restrict__ hidx,    // B,Q,K
                            const float* __restrict__ oidx,    // B,Q,K
                            const float* __restrict__ out_scores, // B,K
                            const float* __restrict__ out_labels, // B,K
                            float* __restrict__ out_pair) {       // B,117,100,101
    int b = blockIdx.x;
    int tid = threadIdx.x;
    __shared__ int   sh_h[QQ];
    __shared__ int   sh_o[QQ];
    __shared__ float sh_ms[QQ];
    __shared__ float sh_coef[QQ];

    if (tid < QQ) {
        const float* hp = hidx + ((size_t)b * QQ + tid) * KK;
        const float* op = oidx + ((size_t)b * QQ + tid) * KK;
        float bh = hp[0]; int ih = 0;
        float bo = op[0]; int io = 0;
        for (int k = 1; k < KK; ++k) {
            float v = hp[k]; if (v > bh) { bh = v; ih = k; }
            float w = op[k]; if (w > bo) { bo = w; io = k; }
        }
        sh_h[tid] = ih;
        sh_o[tid] = io;
        float x = actions[((size_t)b * QQ + tid) * AA + (AA - 1)];
        sh_ms[tid] = 1.f - 1.f / (1.f + expf(-x));
    }
    __syncthreads();

    if (tid < QQ) {
        int f = sh_h[tid] * KP1 + sh_o[tid];
        float myms = sh_ms[tid];
        bool win = true;
        for (int q = 0; q < QQ; ++q) {
            if (sh_h[q] * KP1 + sh_o[q] == f) {
                float m2 = sh_ms[q];
                if (m2 > myms || (m2 == myms && q < tid)) { win = false; break; }
            }
        }
        sh_coef[tid] = myms * (win ? 2.f : 1.f);
    }
    __syncthreads();

    const int total = QQ * AM1;
    for (int idx = tid; idx < total; idx += blockDim.x) {
        int q = idx / AM1;
        int a = idx - q * AM1;
        int h = sh_h[q];
        int o = sh_o[q];
        // masks (scores are softmax probs: > 0 always, but compute exactly)
        float hm = (out_labels[b * KK + h] == 1.0f && out_scores[b * KK + h] > 0.0f) ? 1.f : 0.f;
        if (hm == 0.f) continue; // value would be 0; output already zeroed
        float om = (out_scores[b * KK + o] > 0.0f) ? 1.f : 0.f;
        if (om == 0.f) continue;
        float x = actions[((size_t)b * QQ + q) * AA + a];
        float act = 1.f / (1.f + expf(-x));
        float val = sh_coef[q] * act;
        size_t oi = (((size_t)(b * AM1 + a)) * KK + h) * KP1 + o;
        atomicAdd(out_pair + oi, val);
    }
}

extern "C" void kernel_launch(void* const* d_in, const int* in_sizes, int n_in,
                              void* d_out, int out_size, void* d_ws, size_t ws_size,
                              hipStream_t stream) {
    const float* pred_logits  = (const float*)d_in[0];
    const float* pred_boxes   = (const float*)d_in[1];
    const float* pred_actions = (const float*)d_in[2];
    const float* pred_hidx    = (const float*)d_in[3];
    const float* pred_oidx    = (const float*)d_in[4];
    const int*   target_sizes = (const int*)d_in[5];

    float* out = (float*)d_out;
    float* out_scores = out;                      // B*K
    float* out_labels = out + BB * KK;            // B*K
    float* out_boxes  = out + 2 * BB * KK;        // B*K*4
    float* out_pair   = out + 6 * BB * KK;        // B*117*100*101

    // Zero the entire output (pair_score is sparse; harness does not re-zero
    // between timed replays).
    hipMemsetAsync(d_out, 0, (size_t)out_size * sizeof(float), stream);

    score_box_kernel<<<BB, 128, 0, stream>>>(pred_logits, pred_boxes, target_sizes,
                                             out_scores, out_labels, out_boxes);

    pair_kernel<<<BB, 256, 0, stream>>>(pred_actions, pred_hidx, pred_oidx,
                                        out_scores, out_labels, out_pair);
}